// Round 6
// baseline (224.561 us; speedup 1.0000x reference)
//
#include <hip/hip_runtime.h>
#include <math.h>

#define B_ 16
#define D_ 128
#define LC_ 2048
#define LQ_ 512
#define SHIFT_ 12.0f

typedef unsigned short ushort_t;
typedef short short8 __attribute__((ext_vector_type(8)));
typedef float f32x4 __attribute__((ext_vector_type(4)));

__device__ __forceinline__ ushort_t f2bf(float f) {
    union { float f; unsigned int u; } v; v.f = f;
    unsigned int r = (v.u + 0x7FFFu + ((v.u >> 16) & 1u)) >> 16;
    return (ushort_t)r;
}
__device__ __forceinline__ float bf2f(ushort_t h) {
    union { unsigned int u; float f; } v; v.u = ((unsigned int)h) << 16;
    return v.f;
}
__device__ __forceinline__ void gld16(const void* g, void* l) {
    __builtin_amdgcn_global_load_lds(
        (const __attribute__((address_space(1))) void*)g,
        (__attribute__((address_space(3))) void*)l, 16, 0, 0);
}
#define MFMA16(a, b, c) __builtin_amdgcn_mfma_f32_16x16x32_bf16((a), (b), (c), 0, 0, 0)

// ---------------------------------------------------------------------------
// k_prep: per 64x64 tile of a [D][L] fp32 matrix: write bf16 cast copy
// ([d][l]) and bf16 transpose ([l][d], optional *scale[d]).
// ---------------------------------------------------------------------------
__global__ __launch_bounds__(256) void k_prep(
        const float* __restrict__ src, const float* __restrict__ scale,
        ushort_t* __restrict__ dst_cast, ushort_t* __restrict__ dst_t, int L) {
    __shared__ __align__(16) ushort_t lt[64 * 74];   // [d_local][c_local], pitch 74
    const int b = blockIdx.z, d0 = blockIdx.y * 64, l0 = blockIdx.x * 64;
    const int t = threadIdx.x;
    const int cp = t & 31;        // c-pair
    const int dr = t >> 5;        // 0..7
    const float* S = src + ((size_t)b * D_ + d0) * L + l0;
    #pragma unroll
    for (int i = 0; i < 8; ++i) {
        int d = i * 8 + dr;
        float2 v = *(const float2*)&S[(size_t)d * L + 2 * cp];
        unsigned int cpk = (unsigned int)f2bf(v.x) | ((unsigned int)f2bf(v.y) << 16);
        *(unsigned int*)(dst_cast + ((size_t)b * D_ + d0 + d) * L + l0 + 2 * cp) = cpk;
        float sc = scale ? scale[d0 + d] : 1.0f;
        unsigned int spk = (unsigned int)f2bf(v.x * sc) | ((unsigned int)f2bf(v.y * sc) << 16);
        *(unsigned int*)(lt + d * 74 + 2 * cp) = spk;
    }
    __syncthreads();
    const int c = t >> 2, dch = (t & 3) * 16;
    union { ushort_t u16[16]; uint4 u4[2]; } tmp;
    #pragma unroll
    for (int j = 0; j < 16; ++j) tmp.u16[j] = lt[(dch + j) * 74 + c];
    ushort_t* dr_ = dst_t + ((size_t)b * L + l0 + c) * D_ + d0 + dch;
    *(uint4*)dr_ = tmp.u4[0];
    *(uint4*)(dr_ + 8) = tmp.u4[1];
}

// ---------------------------------------------------------------------------
// k_subs: sub0[b,c], sub1[b,q] (+bias); also zero rowZ/colZ for the atomics.
// ---------------------------------------------------------------------------
__global__ __launch_bounds__(256) void k_subs(
        const float* __restrict__ C, const float* __restrict__ Q,
        const float* __restrict__ w4C, const float* __restrict__ w4Q,
        const float* __restrict__ bias,
        float* __restrict__ sub0, float* __restrict__ sub1,
        float* __restrict__ rowZ, float* __restrict__ colZ) {
    int bid = blockIdx.x;
    const int nb0 = B_ * (LC_ / 256);   // 128
    if (bid < nb0) {
        int b = bid / (LC_ / 256);
        int c = (bid % (LC_ / 256)) * 256 + threadIdx.x;
        const float* Cb = C + (size_t)b * D_ * LC_;
        float acc = 0.f;
        #pragma unroll 8
        for (int d = 0; d < D_; ++d) acc += Cb[(size_t)d * LC_ + c] * w4C[d];
        sub0[b * LC_ + c] = acc;
        rowZ[b * LC_ + c] = 0.f;
    } else {
        int id = bid - nb0;
        int b = id / (LQ_ / 256);
        int q = (id % (LQ_ / 256)) * 256 + threadIdx.x;
        const float* Qb = Q + (size_t)b * D_ * LQ_;
        float acc = bias[0];
        #pragma unroll 8
        for (int d = 0; d < D_; ++d) acc += Qb[(size_t)d * LQ_ + q] * w4Q[d];
        sub1[b * LQ_ + q] = acc;
        colZ[b * LQ_ + q] = 0.f;
    }
}

// ---------------------------------------------------------------------------
// k_score: 128x128 S-tile via MFMA (K=d=128). Epilogue: E=exp(S-SHIFT),
// q-masked, bounced through LDS and stored coalesced as E[c][q] bf16.
// rowZ/colZ softmax denominators accumulated via shfl-reduce + atomics.
// grid (LQ/128, LC/128, B), 256 thr (4 waves, 2x2 of 64x64).
// ---------------------------------------------------------------------------
__global__ __launch_bounds__(256) void k_score(
        const ushort_t* __restrict__ Ct_bf, const ushort_t* __restrict__ Qt_bf,
        const float* __restrict__ sub0, const float* __restrict__ sub1,
        const int* __restrict__ Cmask, const int* __restrict__ Qmask,
        ushort_t* __restrict__ E_bf,
        float* __restrict__ rowZ, float* __restrict__ colZ) {
    __shared__ __align__(16) ushort_t smem[2 * 128 * 128];   // As | Bs ; reused: Etile
    ushort_t* As = smem;
    ushort_t* Bs = smem + 128 * 128;
    ushort_t* Etile = smem;          // [c][q] XOR-chunk layout, 32 KB
    __shared__ float s0s[128], s1s[128], cms[128], qms[128];
    const int b = blockIdx.z, c0 = blockIdx.y * 128, q0 = blockIdx.x * 128;
    const int tid = threadIdx.x, w = tid >> 6, lane = tid & 63;
    const int l15 = lane & 15, l4 = lane >> 4;
    const int wm = w >> 1, wn = w & 1;
    if (tid < 128) {
        s0s[tid] = sub0[b * LC_ + c0 + tid];
        cms[tid] = Cmask[b * LC_ + c0 + tid] ? 1.f : 0.f;
    } else {
        int t2 = tid - 128;
        s1s[t2] = sub1[b * LQ_ + q0 + t2];
        qms[t2] = Qmask[b * LQ_ + q0 + t2] ? 1.f : 0.f;
    }
    const ushort_t* Ab = Ct_bf + ((size_t)b * LC_ + c0) * D_;
    const ushort_t* Bb = Qt_bf + ((size_t)b * LQ_ + q0) * D_;
    #pragma unroll
    for (int i = 0; i < 8; ++i) {
        int r0 = w * 32 + i * 4;
        int row = r0 + l4;
        int ch = l15 ^ (row & 7);           // pre-swizzled source, linear LDS dest
        gld16(Ab + (size_t)row * 128 + ch * 8, As + r0 * 128);
        gld16(Bb + (size_t)row * 128 + ch * 8, Bs + r0 * 128);
    }
    __syncthreads();
    f32x4 acc[4][4];
    const f32x4 z4 = {0.f, 0.f, 0.f, 0.f};
    #pragma unroll
    for (int i = 0; i < 4; ++i)
        #pragma unroll
        for (int j = 0; j < 4; ++j) acc[i][j] = z4;
    #pragma unroll
    for (int ks = 0; ks < 4; ++ks) {
        short8 af[4], bfr[4];
        #pragma unroll
        for (int mi = 0; mi < 4; ++mi) {
            int row = wm * 64 + mi * 16 + l15;
            int ch = (ks * 4 + l4) ^ (row & 7);
            af[mi] = *(const short8*)(As + row * 128 + ch * 8);
        }
        #pragma unroll
        for (int ni = 0; ni < 4; ++ni) {
            int row = wn * 64 + ni * 16 + l15;
            int ch = (ks * 4 + l4) ^ (row & 7);
            bfr[ni] = *(const short8*)(Bs + row * 128 + ch * 8);
        }
        #pragma unroll
        for (int mi = 0; mi < 4; ++mi)
            #pragma unroll
            for (int ni = 0; ni < 4; ++ni)
                acc[mi][ni] = MFMA16(af[mi], bfr[ni], acc[mi][ni]);
    }
    __syncthreads();        // all frag reads done before Etile overwrites As
    // epilogue: E = exp(S-SHIFT)*qm -> LDS tile; rowZ/colZ partials
    float rs[4][4];
    float cs[4] = {0.f, 0.f, 0.f, 0.f};
    #pragma unroll
    for (int mi = 0; mi < 4; ++mi)
        #pragma unroll
        for (int r = 0; r < 4; ++r) rs[mi][r] = 0.f;
    #pragma unroll
    for (int mi = 0; mi < 4; ++mi) {
        #pragma unroll
        for (int ni = 0; ni < 4; ++ni) {
            int q_l = wn * 64 + ni * 16 + l15;
            float qm = qms[q_l], s1v = s1s[q_l];
            #pragma unroll
            for (int r = 0; r < 4; ++r) {
                int c_l = wm * 64 + mi * 16 + l4 * 4 + r;
                float Sv = acc[mi][ni][r] + s0s[c_l] + s1v;
                float e = __expf(Sv - SHIFT_);
                ushort_t e1u = f2bf(e * qm);
                float e1f = bf2f(e1u);
                rs[mi][r] += e1f;
                cs[ni] += e1f * cms[c_l];
                Etile[c_l * 128 + (((q_l >> 3) ^ (c_l & 7)) * 8) + (q_l & 7)] = e1u;
            }
        }
    }
    __syncthreads();
    // coalesced store: each wave writes 4 complete 256B rows per pass
    #pragma unroll
    for (int pass = 0; pass < 8; ++pass) {
        int c = pass * 16 + (tid >> 4);
        int j = tid & 15;
        uint4 v = *(const uint4*)(Etile + c * 128 + ((j ^ (c & 7)) * 8));
        *(uint4*)(E_bf + ((size_t)b * LC_ + c0 + c) * LQ_ + q0 + j * 8) = v;
    }
    #pragma unroll
    for (int mi = 0; mi < 4; ++mi)
        #pragma unroll
        for (int r = 0; r < 4; ++r) {
            float v = rs[mi][r];
            v += __shfl_xor(v, 1); v += __shfl_xor(v, 2);
            v += __shfl_xor(v, 4); v += __shfl_xor(v, 8);
            if (l15 == 0)
                atomicAdd(&rowZ[b * LC_ + c0 + wm * 64 + mi * 16 + l4 * 4 + r], v);
        }
    #pragma unroll
    for (int ni = 0; ni < 4; ++ni) {
        float v = cs[ni];
        v += __shfl_xor(v, 16); v += __shfl_xor(v, 32);
        if (l4 == 0)
            atomicAdd(&colZ[b * LQ_ + q0 + wn * 64 + ni * 16 + l15], v);
    }
}

// ---------------------------------------------------------------------------
// k_tpart: T[b][q][d] += sum_{c in chunk} (E[c][q]*cm[c]) * Cb[d][c]  (MFMA,
// fp32 atomic accumulate). A-operand transposed-staged from E[c][q] via LDS.
// grid (LQ/128, nsplit, B), 256 thr.
// ---------------------------------------------------------------------------
__global__ __launch_bounds__(256) void k_tpart(
        const ushort_t* __restrict__ E_bf, const ushort_t* __restrict__ Cb_bf,
        const int* __restrict__ Cmask, float* __restrict__ T, int chunk) {
    __shared__ __align__(16) ushort_t At[128 * 64];  // [q][c] XOR-chunk layout
    __shared__ __align__(16) ushort_t Bs[128 * 64];  // [d][c] XOR (gld16 staged)
    const int b = blockIdx.z, sp = blockIdx.y, q0 = blockIdx.x * 128;
    const int tid = threadIdx.x, w = tid >> 6, lane = tid & 63;
    const int l15 = lane & 15, l4 = lane >> 4;
    const int l8 = lane >> 3, ch0 = lane & 7;
    const int wm = w >> 1, wn = w & 1;
    const int cbeg = sp * chunk;
    const ushort_t* Bb = Cb_bf + (size_t)b * D_ * LC_ + cbeg;
    const int* cm = Cmask + b * LC_;
    const int c_l = tid >> 2, qq = tid & 3;          // transpose-stage mapping
    f32x4 acc[4][4];
    const f32x4 z4 = {0.f, 0.f, 0.f, 0.f};
    #pragma unroll
    for (int i = 0; i < 4; ++i)
        #pragma unroll
        for (int j = 0; j < 4; ++j) acc[i][j] = z4;
    for (int kk = 0; kk < chunk / 64; ++kk) {
        __syncthreads();
        #pragma unroll
        for (int i = 0; i < 4; ++i) {                // B: Cb rows d, gld16 direct
            int r0 = w * 32 + i * 8;
            int row = r0 + l8;
            int ch = ch0 ^ (row & 7);
            gld16(Bb + (size_t)row * LC_ + kk * 64 + ch * 8, Bs + r0 * 64);
        }
        {                                            // A: E transpose-stage + cmask
            int cg = cbeg + kk * 64 + c_l;
            unsigned int keep = cm[cg] ? 0xFFFFFFFFu : 0u;
            const ushort_t* src = E_bf + ((size_t)b * LC_ + cg) * LQ_ + q0 + qq * 32;
            #pragma unroll
            for (int u = 0; u < 4; ++u) {
                union { uint4 v; ushort_t s[8]; } d;
                d.v = *(const uint4*)(src + u * 8);
                d.v.x &= keep; d.v.y &= keep; d.v.z &= keep; d.v.w &= keep;
                #pragma unroll
                for (int e = 0; e < 8; ++e) {
                    int q = qq * 32 + u * 8 + e;
                    At[q * 64 + (((c_l >> 3) ^ (q & 7)) * 8) + (c_l & 7)] = d.s[e];
                }
            }
        }
        __syncthreads();
        #pragma unroll
        for (int ks = 0; ks < 2; ++ks) {
            short8 af[4], bfr[4];
            #pragma unroll
            for (int mi = 0; mi < 4; ++mi) {
                int row = wm * 64 + mi * 16 + l15;
                int ch = (ks * 4 + l4) ^ (row & 7);
                af[mi] = *(const short8*)(At + row * 64 + ch * 8);
            }
            #pragma unroll
            for (int ni = 0; ni < 4; ++ni) {
                int row = wn * 64 + ni * 16 + l15;
                int ch = (ks * 4 + l4) ^ (row & 7);
                bfr[ni] = *(const short8*)(Bs + row * 64 + ch * 8);
            }
            #pragma unroll
            for (int mi = 0; mi < 4; ++mi)
                #pragma unroll
                for (int ni = 0; ni < 4; ++ni)
                    acc[mi][ni] = MFMA16(af[mi], bfr[ni], acc[mi][ni]);
        }
    }
    float* Tp = T + ((size_t)b * LQ_ + q0) * D_;
    #pragma unroll
    for (int mi = 0; mi < 4; ++mi)
        #pragma unroll
        for (int ni = 0; ni < 4; ++ni)
            #pragma unroll
            for (int r = 0; r < 4; ++r)
                atomicAdd(&Tp[(size_t)(wm * 64 + mi * 16 + l4 * 4 + r) * D_ +
                              wn * 64 + ni * 16 + l15], acc[mi][ni][r]);
}

// ---------------------------------------------------------------------------
// k_treduce: Tt_bf[b][d][q] = bf16( T[b][q][d] / colZ[q] )  (transpose bounce)
// grid (LQ/64, B), 256 thr.
// ---------------------------------------------------------------------------
__global__ __launch_bounds__(256) void k_treduce(
        const float* __restrict__ T, const float* __restrict__ colZ,
        ushort_t* __restrict__ Tt_bf) {
    __shared__ __align__(16) ushort_t lt[128 * 72];   // [d][q], pitch 72
    const int b = blockIdx.y, q0 = blockIdx.x * 64;
    const int t = threadIdx.x;
    const int q = t >> 2, dp = t & 3;
    float r = 1.0f / (colZ[b * LQ_ + q0 + q] + 1e-30f);
    const float4* base = (const float4*)(T + ((size_t)b * LQ_ + q0 + q) * D_);
    #pragma unroll
    for (int i = 0; i < 8; ++i) {
        int d4 = dp + i * 4;
        float4 s = base[d4];
        int d = d4 * 4;
        lt[(d + 0) * 72 + q] = f2bf(s.x * r);
        lt[(d + 1) * 72 + q] = f2bf(s.y * r);
        lt[(d + 2) * 72 + q] = f2bf(s.z * r);
        lt[(d + 3) * 72 + q] = f2bf(s.w * r);
    }
    __syncthreads();
    const int d = t >> 1, half = t & 1;
    ushort_t* dst = Tt_bf + ((size_t)b * D_ + d) * LQ_ + q0 + half * 32;
    #pragma unroll
    for (int j = 0; j < 4; ++j)
        *(uint4*)(dst + j * 8) = *(const uint4*)(lt + d * 72 + half * 32 + j * 8);
}

// ---------------------------------------------------------------------------
// k_out: D1[d][c] = sum_q Qb[d][q]*E[c][q];  D2[d][c] = sum_q T'[d][q]*E[c][q]
// out = [Ct, A, Ct*A, Ct*Bm] with A = D1/rowZ, Bm = D2/rowZ.
// grid (LC/64, B), 256 thr. M=d(128), N=c(64), K=q=512 (8 iters of 64).
// ---------------------------------------------------------------------------
__global__ __launch_bounds__(256) void k_out(
        const ushort_t* __restrict__ E_bf, const ushort_t* __restrict__ Qb_bf,
        const ushort_t* __restrict__ Tt_bf, const float* __restrict__ C,
        const float* __restrict__ rowZ, float* __restrict__ out) {
    __shared__ __align__(16) ushort_t Qs[128 * 64];
    __shared__ __align__(16) ushort_t Ts[128 * 64];
    __shared__ __align__(16) ushort_t Es[64 * 64];
    __shared__ float rrs[64];
    const int b = blockIdx.y, c0 = blockIdx.x * 64;
    const int tid = threadIdx.x, w = tid >> 6, lane = tid & 63;
    const int l15 = lane & 15, l4 = lane >> 4;
    const int l8 = lane >> 3, ch0 = lane & 7;
    const int wm = w >> 1, wn = w & 1;
    if (tid < 64) rrs[tid] = 1.0f / (rowZ[b * LC_ + c0 + tid] + 1e-30f);
    const ushort_t* Qb = Qb_bf + (size_t)b * D_ * LQ_;
    const ushort_t* Tb = Tt_bf + (size_t)b * D_ * LQ_;
    const ushort_t* Eb = E_bf + ((size_t)b * LC_ + c0) * LQ_;
    f32x4 accA[4][2], accB[4][2];
    const f32x4 z4 = {0.f, 0.f, 0.f, 0.f};
    #pragma unroll
    for (int i = 0; i < 4; ++i)
        #pragma unroll
        for (int j = 0; j < 2; ++j) { accA[i][j] = z4; accB[i][j] = z4; }
    for (int kk = 0; kk < 8; ++kk) {
        __syncthreads();
        #pragma unroll
        for (int i = 0; i < 4; ++i) {
            int r0 = w * 32 + i * 8;
            int row = r0 + l8;
            int ch = ch0 ^ (row & 7);
            gld16(Qb + (size_t)row * LQ_ + kk * 64 + ch * 8, Qs + r0 * 64);
            gld16(Tb + (size_t)row * LQ_ + kk * 64 + ch * 8, Ts + r0 * 64);
        }
        #pragma unroll
        for (int i = 0; i < 2; ++i) {
            int r0 = w * 16 + i * 8;
            int row = r0 + l8;
            int ch = ch0 ^ (row & 7);
            gld16(Eb + (size_t)row * LQ_ + kk * 64 + ch * 8, Es + r0 * 64);
        }
        __syncthreads();
        #pragma unroll
        for (int ks = 0; ks < 2; ++ks) {
            short8 aq[4], at[4], be[2];
            #pragma unroll
            for (int mi = 0; mi < 4; ++mi) {
                int row = wm * 64 + mi * 16 + l15;
                int ch = (ks * 4 + l4) ^ (row & 7);
                aq[mi] = *(const short8*)(Qs + row * 64 + ch * 8);
                at[mi] = *(const short8*)(Ts + row * 64 + ch * 8);
            }
            #pragma unroll
            for (int ni = 0; ni < 2; ++ni) {
                int row = wn * 32 + ni * 16 + l15;
                int ch = (ks * 4 + l4) ^ (row & 7);
                be[ni] = *(const short8*)(Es + row * 64 + ch * 8);
            }
            #pragma unroll
            for (int mi = 0; mi < 4; ++mi)
                #pragma unroll
                for (int ni = 0; ni < 2; ++ni) {
                    accA[mi][ni] = MFMA16(aq[mi], be[ni], accA[mi][ni]);
                    accB[mi][ni] = MFMA16(at[mi], be[ni], accB[mi][ni]);
                }
        }
    }
    #pragma unroll
    for (int mi = 0; mi < 4; ++mi)
        #pragma unroll
        for (int ni = 0; ni < 2; ++ni) {
            int c_l = wn * 32 + ni * 16 + l15;
            int cg = c0 + c_l;
            float rr = rrs[c_l];
            #pragma unroll
            for (int r = 0; r < 4; ++r) {
                int d = wm * 64 + mi * 16 + l4 * 4 + r;
                float ct = C[((size_t)b * D_ + d) * LC_ + cg];
                float av = accA[mi][ni][r] * rr;
                float bv = accB[mi][ni][r] * rr;
                size_t o = ((size_t)b * 4 * D_ + d) * LC_ + cg;
                out[o] = ct;
                out[o + (size_t)D_ * LC_] = av;
                out[o + (size_t)2 * D_ * LC_] = ct * av;
                out[o + (size_t)3 * D_ * LC_] = ct * bv;
            }
        }
}

// ---------------------------------------------------------------------------
extern "C" void kernel_launch(void* const* d_in, const int* in_sizes, int n_in,
                              void* d_out, int out_size, void* d_ws, size_t ws_size,
                              hipStream_t stream) {
    (void)in_sizes; (void)n_in; (void)out_size; (void)ws_size;
    const float* C     = (const float*)d_in[0];
    const float* Q     = (const float*)d_in[1];
    const int*   Cmask = (const int*)d_in[2];
    const int*   Qmask = (const int*)d_in[3];
    const float* w4C   = (const float*)d_in[4];
    const float* w4Q   = (const float*)d_in[5];
    const float* w4mlu = (const float*)d_in[6];
    const float* bias  = (const float*)d_in[7];
    float* out = (float*)d_out;

    char* p = (char*)d_ws;
    auto alloc = [&](size_t bytes) -> void* {
        void* r = (void*)p; p += (bytes + 255) & ~(size_t)255; return r;
    };
    ushort_t* Ct_bf = (ushort_t*)alloc((size_t)B_ * LC_ * D_ * 2);   // [b][c][d] *w4mlu
    ushort_t* Qt_bf = (ushort_t*)alloc((size_t)B_ * LQ_ * D_ * 2);   // [b][q][d]
    ushort_t* Cb_bf = (ushort_t*)alloc((size_t)B_ * D_ * LC_ * 2);   // [b][d][c]
    ushort_t* Qb_bf = (ushort_t*)alloc((size_t)B_ * D_ * LQ_ * 2);   // [b][d][q]
    ushort_t* E_bf  = (ushort_t*)alloc((size_t)B_ * LC_ * LQ_ * 2);  // exp, q-masked
    ushort_t* Tt_bf = (ushort_t*)alloc((size_t)B_ * D_ * LQ_ * 2);   // [b][d][q]
    float* sub0 = (float*)alloc((size_t)B_ * LC_ * 4);
    float* sub1 = (float*)alloc((size_t)B_ * LQ_ * 4);
    float* rowZ = (float*)alloc((size_t)B_ * LC_ * 4);
    float* colZ = (float*)alloc((size_t)B_ * LQ_ * 4);
    float* Tf   = (float*)alloc((size_t)B_ * LQ_ * D_ * 4);          // [b][q][d] fp32

    const int nsplit = 16, chunk = LC_ / nsplit;   // 128

    k_prep<<<dim3(LC_ / 64, 2, B_), 256, 0, stream>>>(C, w4mlu, Cb_bf, Ct_bf, LC_);
    k_prep<<<dim3(LQ_ / 64, 2, B_), 256, 0, stream>>>(Q, nullptr, Qb_bf, Qt_bf, LQ_);
    k_subs<<<B_ * (LC_ / 256) + B_ * (LQ_ / 256), 256, 0, stream>>>(
        C, Q, w4C, w4Q, bias, sub0, sub1, rowZ, colZ);
    hipMemsetAsync(Tf, 0, (size_t)B_ * LQ_ * D_ * 4, stream);
    k_score<<<dim3(LQ_ / 128, LC_ / 128, B_), 256, 0, stream>>>(
        Ct_bf, Qt_bf, sub0, sub1, Cmask, Qmask, E_bf, rowZ, colZ);
    k_tpart<<<dim3(LQ_ / 128, nsplit, B_), 256, 0, stream>>>(
        E_bf, Cb_bf, Cmask, Tf, chunk);
    k_treduce<<<dim3(LQ_ / 64, B_), 256, 0, stream>>>(Tf, colZ, Tt_bf);
    k_out<<<dim3(LC_ / 64, B_), 256, 0, stream>>>(E_bf, Qb_bf, Tt_bf, C, rowZ, out);
}

// Round 8
// 182.193 us; speedup vs baseline: 1.2325x; 1.2325x over previous
//
#include <hip/hip_runtime.h>
#include <math.h>

#define B_ 16
#define D_ 128
#define LC_ 2048
#define LQ_ 512
#define SHIFT_ 12.0f
#define NSPLIT_ 8

typedef unsigned short ushort_t;
typedef short short8 __attribute__((ext_vector_type(8)));
typedef float f32x4 __attribute__((ext_vector_type(4)));

__device__ __forceinline__ ushort_t f2bf(float f) {
    union { float f; unsigned int u; } v; v.f = f;
    unsigned int r = (v.u + 0x7FFFu + ((v.u >> 16) & 1u)) >> 16;
    return (ushort_t)r;
}
__device__ __forceinline__ float bf2f(ushort_t h) {
    union { unsigned int u; float f; } v; v.u = ((unsigned int)h) << 16;
    return v.f;
}
__device__ __forceinline__ void gld16(const void* g, void* l) {
    __builtin_amdgcn_global_load_lds(
        (const __attribute__((address_space(1))) void*)g,
        (__attribute__((address_space(3))) void*)l, 16, 0, 0);
}
#define MFMA16(a, b, c) __builtin_amdgcn_mfma_f32_16x16x32_bf16((a), (b), (c), 0, 0, 0)

// ---------------------------------------------------------------------------
// k_prep: per 64x64 tile of a [D][L] fp32 matrix: write bf16 cast copy
// ([d][l]) and bf16 transpose ([l][d], optional *scale[d]).
// ---------------------------------------------------------------------------
__global__ __launch_bounds__(256) void k_prep(
        const float* __restrict__ src, const float* __restrict__ scale,
        ushort_t* __restrict__ dst_cast, ushort_t* __restrict__ dst_t, int L) {
    __shared__ __align__(16) ushort_t lt[64 * 74];   // [d_local][c_local], pitch 74
    const int b = blockIdx.z, d0 = blockIdx.y * 64, l0 = blockIdx.x * 64;
    const int t = threadIdx.x;
    const int cp = t & 31;        // c-pair
    const int dr = t >> 5;        // 0..7
    const float* S = src + ((size_t)b * D_ + d0) * L + l0;
    #pragma unroll
    for (int i = 0; i < 8; ++i) {
        int d = i * 8 + dr;
        float2 v = *(const float2*)&S[(size_t)d * L + 2 * cp];
        unsigned int cpk = (unsigned int)f2bf(v.x) | ((unsigned int)f2bf(v.y) << 16);
        *(unsigned int*)(dst_cast + ((size_t)b * D_ + d0 + d) * L + l0 + 2 * cp) = cpk;
        float sc = scale ? scale[d0 + d] : 1.0f;
        unsigned int spk = (unsigned int)f2bf(v.x * sc) | ((unsigned int)f2bf(v.y * sc) << 16);
        *(unsigned int*)(lt + d * 74 + 2 * cp) = spk;
    }
    __syncthreads();
    const int c = t >> 2, dch = (t & 3) * 16;
    union { ushort_t u16[16]; uint4 u4[2]; } tmp;
    #pragma unroll
    for (int j = 0; j < 16; ++j) tmp.u16[j] = lt[(dch + j) * 74 + c];
    ushort_t* dr_ = dst_t + ((size_t)b * L + l0 + c) * D_ + d0 + dch;
    *(uint4*)dr_ = tmp.u4[0];
    *(uint4*)(dr_ + 8) = tmp.u4[1];
}

// ---------------------------------------------------------------------------
// k_subs: sub0[b,c], sub1[b,q] (+bias); also zero rowZ/colZ for the atomics.
// ---------------------------------------------------------------------------
__global__ __launch_bounds__(256) void k_subs(
        const float* __restrict__ C, const float* __restrict__ Q,
        const float* __restrict__ w4C, const float* __restrict__ w4Q,
        const float* __restrict__ bias,
        float* __restrict__ sub0, float* __restrict__ sub1,
        float* __restrict__ rowZ, float* __restrict__ colZ) {
    int bid = blockIdx.x;
    const int nb0 = B_ * (LC_ / 256);   // 128
    if (bid < nb0) {
        int b = bid / (LC_ / 256);
        int c = (bid % (LC_ / 256)) * 256 + threadIdx.x;
        const float* Cb = C + (size_t)b * D_ * LC_;
        float acc = 0.f;
        #pragma unroll 8
        for (int d = 0; d < D_; ++d) acc += Cb[(size_t)d * LC_ + c] * w4C[d];
        sub0[b * LC_ + c] = acc;
        rowZ[b * LC_ + c] = 0.f;
    } else {
        int id = bid - nb0;
        int b = id / (LQ_ / 256);
        int q = (id % (LQ_ / 256)) * 256 + threadIdx.x;
        const float* Qb = Q + (size_t)b * D_ * LQ_;
        float acc = bias[0];
        #pragma unroll 8
        for (int d = 0; d < D_; ++d) acc += Qb[(size_t)d * LQ_ + q] * w4Q[d];
        sub1[b * LQ_ + q] = acc;
        colZ[b * LQ_ + q] = 0.f;
    }
}

// ---------------------------------------------------------------------------
// k_score: 128x128 S-tile via MFMA (K=d=128). Epilogue: E=exp(S-SHIFT),
// q-masked, bounced through LDS and stored coalesced as E[c][q] bf16.
// rowZ/colZ softmax denominators accumulated via shfl-reduce + atomics.
// grid (LQ/128, LC/128, B), 256 thr (4 waves, 2x2 of 64x64).
// ---------------------------------------------------------------------------
__global__ __launch_bounds__(256) void k_score(
        const ushort_t* __restrict__ Ct_bf, const ushort_t* __restrict__ Qt_bf,
        const float* __restrict__ sub0, const float* __restrict__ sub1,
        const int* __restrict__ Cmask, const int* __restrict__ Qmask,
        ushort_t* __restrict__ E_bf,
        float* __restrict__ rowZ, float* __restrict__ colZ) {
    __shared__ __align__(16) ushort_t smem[2 * 128 * 128];   // As | Bs ; reused: Etile
    ushort_t* As = smem;
    ushort_t* Bs = smem + 128 * 128;
    ushort_t* Etile = smem;          // [c][q] XOR-chunk layout, 32 KB
    __shared__ float s0s[128], s1s[128], cms[128], qms[128];
    const int b = blockIdx.z, c0 = blockIdx.y * 128, q0 = blockIdx.x * 128;
    const int tid = threadIdx.x, w = tid >> 6, lane = tid & 63;
    const int l15 = lane & 15, l4 = lane >> 4;
    const int wm = w >> 1, wn = w & 1;
    if (tid < 128) {
        s0s[tid] = sub0[b * LC_ + c0 + tid];
        cms[tid] = Cmask[b * LC_ + c0 + tid] ? 1.f : 0.f;
    } else {
        int t2 = tid - 128;
        s1s[t2] = sub1[b * LQ_ + q0 + t2];
        qms[t2] = Qmask[b * LQ_ + q0 + t2] ? 1.f : 0.f;
    }
    const ushort_t* Ab = Ct_bf + ((size_t)b * LC_ + c0) * D_;
    const ushort_t* Bb = Qt_bf + ((size_t)b * LQ_ + q0) * D_;
    #pragma unroll
    for (int i = 0; i < 8; ++i) {
        int r0 = w * 32 + i * 4;
        int row = r0 + l4;
        int ch = l15 ^ (row & 7);           // pre-swizzled source, linear LDS dest
        gld16(Ab + (size_t)row * 128 + ch * 8, As + r0 * 128);
        gld16(Bb + (size_t)row * 128 + ch * 8, Bs + r0 * 128);
    }
    __syncthreads();
    f32x4 acc[4][4];
    const f32x4 z4 = {0.f, 0.f, 0.f, 0.f};
    #pragma unroll
    for (int i = 0; i < 4; ++i)
        #pragma unroll
        for (int j = 0; j < 4; ++j) acc[i][j] = z4;
    #pragma unroll
    for (int ks = 0; ks < 4; ++ks) {
        short8 af[4], bfr[4];
        #pragma unroll
        for (int mi = 0; mi < 4; ++mi) {
            int row = wm * 64 + mi * 16 + l15;
            int ch = (ks * 4 + l4) ^ (row & 7);
            af[mi] = *(const short8*)(As + row * 128 + ch * 8);
        }
        #pragma unroll
        for (int ni = 0; ni < 4; ++ni) {
            int row = wn * 64 + ni * 16 + l15;
            int ch = (ks * 4 + l4) ^ (row & 7);
            bfr[ni] = *(const short8*)(Bs + row * 128 + ch * 8);
        }
        #pragma unroll
        for (int mi = 0; mi < 4; ++mi)
            #pragma unroll
            for (int ni = 0; ni < 4; ++ni)
                acc[mi][ni] = MFMA16(af[mi], bfr[ni], acc[mi][ni]);
    }
    __syncthreads();        // all frag reads done before Etile overwrites As
    // epilogue: E = exp(S-SHIFT)*qm -> LDS tile; rowZ/colZ partials
    float rs[4][4];
    float cs[4] = {0.f, 0.f, 0.f, 0.f};
    #pragma unroll
    for (int mi = 0; mi < 4; ++mi)
        #pragma unroll
        for (int r = 0; r < 4; ++r) rs[mi][r] = 0.f;
    #pragma unroll
    for (int mi = 0; mi < 4; ++mi) {
        #pragma unroll
        for (int ni = 0; ni < 4; ++ni) {
            int q_l = wn * 64 + ni * 16 + l15;
            float qm = qms[q_l], s1v = s1s[q_l];
            #pragma unroll
            for (int r = 0; r < 4; ++r) {
                int c_l = wm * 64 + mi * 16 + l4 * 4 + r;
                float Sv = acc[mi][ni][r] + s0s[c_l] + s1v;
                float e = __expf(Sv - SHIFT_);
                ushort_t e1u = f2bf(e * qm);
                float e1f = bf2f(e1u);
                rs[mi][r] += e1f;
                cs[ni] += e1f * cms[c_l];
                Etile[c_l * 128 + (((q_l >> 3) ^ (c_l & 7)) * 8) + (q_l & 7)] = e1u;
            }
        }
    }
    __syncthreads();
    // coalesced store: each wave writes 4 complete 256B rows per pass
    #pragma unroll
    for (int pass = 0; pass < 8; ++pass) {
        int c = pass * 16 + (tid >> 4);
        int j = tid & 15;
        uint4 v = *(const uint4*)(Etile + c * 128 + ((j ^ (c & 7)) * 8));
        *(uint4*)(E_bf + ((size_t)b * LC_ + c0 + c) * LQ_ + q0 + j * 8) = v;
    }
    #pragma unroll
    for (int mi = 0; mi < 4; ++mi)
        #pragma unroll
        for (int r = 0; r < 4; ++r) {
            float v = rs[mi][r];
            v += __shfl_xor(v, 1); v += __shfl_xor(v, 2);
            v += __shfl_xor(v, 4); v += __shfl_xor(v, 8);
            if (l15 == 0)
                atomicAdd(&rowZ[b * LC_ + c0 + wm * 64 + mi * 16 + l4 * 4 + r], v);
        }
    #pragma unroll
    for (int ni = 0; ni < 4; ++ni) {
        float v = cs[ni];
        v += __shfl_xor(v, 16); v += __shfl_xor(v, 32);
        if (l4 == 0)
            atomicAdd(&colZ[b * LQ_ + q0 + wn * 64 + ni * 16 + l15], v);
    }
}

// ---------------------------------------------------------------------------
// k_tpart: Tpart[sp][b][q][d] = sum_{c in chunk sp} (E[c][q]*cm[c]) * Cb[d][c]
// (MFMA, regular stores — NO atomics). A-operand transpose-staged from E[c][q].
// grid (LQ/128, NSPLIT_, B), 256 thr.
// ---------------------------------------------------------------------------
__global__ __launch_bounds__(256) void k_tpart(
        const ushort_t* __restrict__ E_bf, const ushort_t* __restrict__ Cb_bf,
        const int* __restrict__ Cmask, float* __restrict__ Tpart, int chunk) {
    __shared__ __align__(16) ushort_t At[128 * 64];  // [q][c] XOR-chunk layout
    __shared__ __align__(16) ushort_t Bs[128 * 64];  // [d][c] XOR (gld16 staged)
    const int b = blockIdx.z, sp = blockIdx.y, q0 = blockIdx.x * 128;
    const int tid = threadIdx.x, w = tid >> 6, lane = tid & 63;
    const int l15 = lane & 15, l4 = lane >> 4;
    const int l8 = lane >> 3, ch0 = lane & 7;
    const int wm = w >> 1, wn = w & 1;
    const int cbeg = sp * chunk;
    const ushort_t* Bb = Cb_bf + (size_t)b * D_ * LC_ + cbeg;
    const int* cm = Cmask + b * LC_;
    const int c_l = tid >> 2, qq = tid & 3;          // transpose-stage mapping
    f32x4 acc[4][4];
    const f32x4 z4 = {0.f, 0.f, 0.f, 0.f};
    #pragma unroll
    for (int i = 0; i < 4; ++i)
        #pragma unroll
        for (int j = 0; j < 4; ++j) acc[i][j] = z4;
    for (int kk = 0; kk < chunk / 64; ++kk) {
        __syncthreads();
        #pragma unroll
        for (int i = 0; i < 4; ++i) {                // B: Cb rows d, gld16 direct
            int r0 = w * 32 + i * 8;
            int row = r0 + l8;
            int ch = ch0 ^ (row & 7);
            gld16(Bb + (size_t)row * LC_ + kk * 64 + ch * 8, Bs + r0 * 64);
        }
        {                                            // A: E transpose-stage + cmask
            int cg = cbeg + kk * 64 + c_l;
            unsigned int keep = cm[cg] ? 0xFFFFFFFFu : 0u;
            const ushort_t* src = E_bf + ((size_t)b * LC_ + cg) * LQ_ + q0 + qq * 32;
            #pragma unroll
            for (int u = 0; u < 4; ++u) {
                union { uint4 v; ushort_t s[8]; } d;
                d.v = *(const uint4*)(src + u * 8);
                d.v.x &= keep; d.v.y &= keep; d.v.z &= keep; d.v.w &= keep;
                #pragma unroll
                for (int e = 0; e < 8; ++e) {
                    int q = qq * 32 + u * 8 + e;
                    At[q * 64 + (((c_l >> 3) ^ (q & 7)) * 8) + (c_l & 7)] = d.s[e];
                }
            }
        }
        __syncthreads();
        #pragma unroll
        for (int ks = 0; ks < 2; ++ks) {
            short8 af[4], bfr[4];
            #pragma unroll
            for (int mi = 0; mi < 4; ++mi) {
                int row = wm * 64 + mi * 16 + l15;
                int ch = (ks * 4 + l4) ^ (row & 7);
                af[mi] = *(const short8*)(At + row * 64 + ch * 8);
            }
            #pragma unroll
            for (int ni = 0; ni < 4; ++ni) {
                int row = wn * 64 + ni * 16 + l15;
                int ch = (ks * 4 + l4) ^ (row & 7);
                bfr[ni] = *(const short8*)(Bs + row * 64 + ch * 8);
            }
            #pragma unroll
            for (int mi = 0; mi < 4; ++mi)
                #pragma unroll
                for (int ni = 0; ni < 4; ++ni)
                    acc[mi][ni] = MFMA16(af[mi], bfr[ni], acc[mi][ni]);
        }
    }
    float* Tp = Tpart + (((size_t)sp * B_ + b) * LQ_ + q0) * D_;
    #pragma unroll
    for (int mi = 0; mi < 4; ++mi)
        #pragma unroll
        for (int ni = 0; ni < 4; ++ni)
            #pragma unroll
            for (int r = 0; r < 4; ++r)
                Tp[(size_t)(wm * 64 + mi * 16 + l4 * 4 + r) * D_ +
                   wn * 64 + ni * 16 + l15] = acc[mi][ni][r];
}

// ---------------------------------------------------------------------------
// k_treduce: Tt_bf[b][d][q] = bf16( sum_sp Tpart[sp][b][q][d] / colZ[q] )
// grid (LQ/64, B), 256 thr; transpose bounce via LDS.
// ---------------------------------------------------------------------------
__global__ __launch_bounds__(256) void k_treduce(
        const float* __restrict__ Tpart, const float* __restrict__ colZ,
        ushort_t* __restrict__ Tt_bf) {
    __shared__ __align__(16) ushort_t lt[128 * 72];   // [d][q], pitch 72
    const int b = blockIdx.y, q0 = blockIdx.x * 64;
    const int t = threadIdx.x;
    const int q = t >> 2, dp = t & 3;
    float r = 1.0f / (colZ[b * LQ_ + q0 + q] + 1e-30f);
    const float4* base = (const float4*)(Tpart + ((size_t)b * LQ_ + q0 + q) * D_);
    const size_t spstr = (size_t)B_ * LQ_ * D_ / 4;
    #pragma unroll
    for (int i = 0; i < 8; ++i) {
        int d4 = dp + i * 4;
        float4 s = {0.f, 0.f, 0.f, 0.f};
        #pragma unroll
        for (int sp = 0; sp < NSPLIT_; ++sp) {
            float4 v = base[(size_t)sp * spstr + d4];
            s.x += v.x; s.y += v.y; s.z += v.z; s.w += v.w;
        }
        int d = d4 * 4;
        lt[(d + 0) * 72 + q] = f2bf(s.x * r);
        lt[(d + 1) * 72 + q] = f2bf(s.y * r);
        lt[(d + 2) * 72 + q] = f2bf(s.z * r);
        lt[(d + 3) * 72 + q] = f2bf(s.w * r);
    }
    __syncthreads();
    const int d = t >> 1, half = t & 1;
    ushort_t* dst = Tt_bf + ((size_t)b * D_ + d) * LQ_ + q0 + half * 32;
    #pragma unroll
    for (int j = 0; j < 4; ++j)
        *(uint4*)(dst + j * 8) = *(const uint4*)(lt + d * 72 + half * 32 + j * 8);
}

// ---------------------------------------------------------------------------
// k_out: D1[d][c] = sum_q Qb[d][q]*E[c][q];  D2[d][c] = sum_q T'[d][q]*E[c][q]
// out = [Ct, A, Ct*A, Ct*Bm] with A = D1/rowZ, Bm = D2/rowZ.
// grid (LC/64, B), 256 thr. M=d(128), N=c(64), K=q=512 (8 iters of 64).
// ---------------------------------------------------------------------------
__global__ __launch_bounds__(256) void k_out(
        const ushort_t* __restrict__ E_bf, const ushort_t* __restrict__ Qb_bf,
        const ushort_t* __restrict__ Tt_bf, const float* __restrict__ C,
        const float* __restrict__ rowZ, float* __restrict__ out) {
    __shared__ __align__(16) ushort_t Qs[128 * 64];
    __shared__ __align__(16) ushort_t Ts[128 * 64];
    __shared__ __align__(16) ushort_t Es[64 * 64];
    __shared__ float rrs[64];
    const int b = blockIdx.y, c0 = blockIdx.x * 64;
    const int tid = threadIdx.x, w = tid >> 6, lane = tid & 63;
    const int l15 = lane & 15, l4 = lane >> 4;
    const int l8 = lane >> 3, ch0 = lane & 7;
    const int wm = w >> 1, wn = w & 1;
    if (tid < 64) rrs[tid] = 1.0f / (rowZ[b * LC_ + c0 + tid] + 1e-30f);
    const ushort_t* Qb = Qb_bf + (size_t)b * D_ * LQ_;
    const ushort_t* Tb = Tt_bf + (size_t)b * D_ * LQ_;
    const ushort_t* Eb = E_bf + ((size_t)b * LC_ + c0) * LQ_;
    f32x4 accA[4][2], accB[4][2];
    const f32x4 z4 = {0.f, 0.f, 0.f, 0.f};
    #pragma unroll
    for (int i = 0; i < 4; ++i)
        #pragma unroll
        for (int j = 0; j < 2; ++j) { accA[i][j] = z4; accB[i][j] = z4; }
    for (int kk = 0; kk < 8; ++kk) {
        __syncthreads();
        #pragma unroll
        for (int i = 0; i < 4; ++i) {
            int r0 = w * 32 + i * 8;
            int row = r0 + l8;
            int ch = ch0 ^ (row & 7);
            gld16(Qb + (size_t)row * LQ_ + kk * 64 + ch * 8, Qs + r0 * 64);
            gld16(Tb + (size_t)row * LQ_ + kk * 64 + ch * 8, Ts + r0 * 64);
        }
        #pragma unroll
        for (int i = 0; i < 2; ++i) {
            int r0 = w * 16 + i * 8;
            int row = r0 + l8;
            int ch = ch0 ^ (row & 7);
            gld16(Eb + (size_t)row * LQ_ + kk * 64 + ch * 8, Es + r0 * 64);
        }
        __syncthreads();
        #pragma unroll
        for (int ks = 0; ks < 2; ++ks) {
            short8 aq[4], at[4], be[2];
            #pragma unroll
            for (int mi = 0; mi < 4; ++mi) {
                int row = wm * 64 + mi * 16 + l15;
                int ch = (ks * 4 + l4) ^ (row & 7);
                aq[mi] = *(const short8*)(Qs + row * 64 + ch * 8);
                at[mi] = *(const short8*)(Ts + row * 64 + ch * 8);
            }
            #pragma unroll
            for (int ni = 0; ni < 2; ++ni) {
                int row = wn * 32 + ni * 16 + l15;
                int ch = (ks * 4 + l4) ^ (row & 7);
                be[ni] = *(const short8*)(Es + row * 64 + ch * 8);
            }
            #pragma unroll
            for (int mi = 0; mi < 4; ++mi)
                #pragma unroll
                for (int ni = 0; ni < 2; ++ni) {
                    accA[mi][ni] = MFMA16(aq[mi], be[ni], accA[mi][ni]);
                    accB[mi][ni] = MFMA16(at[mi], be[ni], accB[mi][ni]);
                }
        }
    }
    #pragma unroll
    for (int mi = 0; mi < 4; ++mi)
        #pragma unroll
        for (int ni = 0; ni < 2; ++ni) {
            int c_l = wn * 32 + ni * 16 + l15;
            int cg = c0 + c_l;
            float rr = rrs[c_l];
            #pragma unroll
            for (int r = 0; r < 4; ++r) {
                int d = wm * 64 + mi * 16 + l4 * 4 + r;
                float ct = C[((size_t)b * D_ + d) * LC_ + cg];
                float av = accA[mi][ni][r] * rr;
                float bv = accB[mi][ni][r] * rr;
                size_t o = ((size_t)b * 4 * D_ + d) * LC_ + cg;
                out[o] = ct;
                out[o + (size_t)D_ * LC_] = av;
                out[o + (size_t)2 * D_ * LC_] = ct * av;
                out[o + (size_t)3 * D_ * LC_] = ct * bv;
            }
        }
}

// ---------------------------------------------------------------------------
extern "C" void kernel_launch(void* const* d_in, const int* in_sizes, int n_in,
                              void* d_out, int out_size, void* d_ws, size_t ws_size,
                              hipStream_t stream) {
    (void)in_sizes; (void)n_in; (void)out_size; (void)ws_size;
    const float* C     = (const float*)d_in[0];
    const float* Q     = (const float*)d_in[1];
    const int*   Cmask = (const int*)d_in[2];
    const int*   Qmask = (const int*)d_in[3];
    const float* w4C   = (const float*)d_in[4];
    const float* w4Q   = (const float*)d_in[5];
    const float* w4mlu = (const float*)d_in[6];
    const float* bias  = (const float*)d_in[7];
    float* out = (float*)d_out;

    char* p = (char*)d_ws;
    auto alloc = [&](size_t bytes) -> void* {
        void* r = (void*)p; p += (bytes + 255) & ~(size_t)255; return r;
    };
    ushort_t* Ct_bf = (ushort_t*)alloc((size_t)B_ * LC_ * D_ * 2);   // [b][c][d] *w4mlu
    ushort_t* Qt_bf = (ushort_t*)alloc((size_t)B_ * LQ_ * D_ * 2);   // [b][q][d]
    ushort_t* Cb_bf = (ushort_t*)alloc((size_t)B_ * D_ * LC_ * 2);   // [b][d][c]
    ushort_t* Qb_bf = (ushort_t*)alloc((size_t)B_ * D_ * LQ_ * 2);   // [b][d][q]
    ushort_t* E_bf  = (ushort_t*)alloc((size_t)B_ * LC_ * LQ_ * 2);  // exp, q-masked
    ushort_t* Tt_bf = (ushort_t*)alloc((size_t)B_ * D_ * LQ_ * 2);   // [b][d][q]
    float* sub0 = (float*)alloc((size_t)B_ * LC_ * 4);
    float* sub1 = (float*)alloc((size_t)B_ * LQ_ * 4);
    float* rowZ = (float*)alloc((size_t)B_ * LC_ * 4);
    float* colZ = (float*)alloc((size_t)B_ * LQ_ * 4);
    float* Tpart = (float*)alloc((size_t)NSPLIT_ * B_ * LQ_ * D_ * 4);  // 32 MB

    const int chunk = LC_ / NSPLIT_;   // 256

    k_prep<<<dim3(LC_ / 64, 2, B_), 256, 0, stream>>>(C, w4mlu, Cb_bf, Ct_bf, LC_);
    k_prep<<<dim3(LQ_ / 64, 2, B_), 256, 0, stream>>>(Q, nullptr, Qb_bf, Qt_bf, LQ_);
    k_subs<<<B_ * (LC_ / 256) + B_ * (LQ_ / 256), 256, 0, stream>>>(
        C, Q, w4C, w4Q, bias, sub0, sub1, rowZ, colZ);
    k_score<<<dim3(LQ_ / 128, LC_ / 128, B_), 256, 0, stream>>>(
        Ct_bf, Qt_bf, sub0, sub1, Cmask, Qmask, E_bf, rowZ, colZ);
    k_tpart<<<dim3(LQ_ / 128, NSPLIT_, B_), 256, 0, stream>>>(
        E_bf, Cb_bf, Cmask, Tpart, chunk);
    k_treduce<<<dim3(LQ_ / 64, B_), 256, 0, stream>>>(Tpart, colZ, Tt_bf);
    k_out<<<dim3(LC_ / 64, B_), 256, 0, stream>>>(E_bf, Qb_bf, Tt_bf, C, rowZ, out);
}

// Round 9
// 180.197 us; speedup vs baseline: 1.2462x; 1.0111x over previous
//
#include <hip/hip_runtime.h>
#include <math.h>

#define B_ 16
#define D_ 128
#define LC_ 2048
#define LQ_ 512
#define SHIFT_ 12.0f
#define NSPLIT_ 4

typedef unsigned short ushort_t;
typedef short short8 __attribute__((ext_vector_type(8)));
typedef float f32x4 __attribute__((ext_vector_type(4)));

__device__ __forceinline__ ushort_t f2bf(float f) {
    union { float f; unsigned int u; } v; v.f = f;
    unsigned int r = (v.u + 0x7FFFu + ((v.u >> 16) & 1u)) >> 16;
    return (ushort_t)r;
}
__device__ __forceinline__ float bf2f(ushort_t h) {
    union { unsigned int u; float f; } v; v.u = ((unsigned int)h) << 16;
    return v.f;
}
__device__ __forceinline__ void gld16(const void* g, void* l) {
    __builtin_amdgcn_global_load_lds(
        (const __attribute__((address_space(1))) void*)g,
        (__attribute__((address_space(3))) void*)l, 16, 0, 0);
}
#define MFMA16(a, b, c) __builtin_amdgcn_mfma_f32_16x16x32_bf16((a), (b), (c), 0, 0, 0)
// At swizzle: free on both write (qq varies (q>>4)&3) and read (l15 varies q&7)
#define SWZA(q) ((((q) & 7) ^ (((q) >> 4) & 3)))

// ---------------------------------------------------------------------------
// k_prep: per 64x64 tile of a [D][L] fp32 matrix: write bf16 cast copy
// ([d][l]) and bf16 transpose ([l][d], optional *scale[d]).
// ---------------------------------------------------------------------------
__global__ __launch_bounds__(256) void k_prep(
        const float* __restrict__ src, const float* __restrict__ scale,
        ushort_t* __restrict__ dst_cast, ushort_t* __restrict__ dst_t, int L) {
    __shared__ __align__(16) ushort_t lt[64 * 74];   // [d_local][c_local], pitch 74
    const int b = blockIdx.z, d0 = blockIdx.y * 64, l0 = blockIdx.x * 64;
    const int t = threadIdx.x;
    const int cp = t & 31;        // c-pair
    const int dr = t >> 5;        // 0..7
    const float* S = src + ((size_t)b * D_ + d0) * L + l0;
    #pragma unroll
    for (int i = 0; i < 8; ++i) {
        int d = i * 8 + dr;
        float2 v = *(const float2*)&S[(size_t)d * L + 2 * cp];
        unsigned int cpk = (unsigned int)f2bf(v.x) | ((unsigned int)f2bf(v.y) << 16);
        *(unsigned int*)(dst_cast + ((size_t)b * D_ + d0 + d) * L + l0 + 2 * cp) = cpk;
        float sc = scale ? scale[d0 + d] : 1.0f;
        unsigned int spk = (unsigned int)f2bf(v.x * sc) | ((unsigned int)f2bf(v.y * sc) << 16);
        *(unsigned int*)(lt + d * 74 + 2 * cp) = spk;
    }
    __syncthreads();
    const int c = t >> 2, dch = (t & 3) * 16;
    union { ushort_t u16[16]; uint4 u4[2]; } tmp;
    #pragma unroll
    for (int j = 0; j < 16; ++j) tmp.u16[j] = lt[(dch + j) * 74 + c];
    ushort_t* dr_ = dst_t + ((size_t)b * L + l0 + c) * D_ + d0 + dch;
    *(uint4*)dr_ = tmp.u4[0];
    *(uint4*)(dr_ + 8) = tmp.u4[1];
}

// ---------------------------------------------------------------------------
// k_subs: sub0[b,c], sub1[b,q] (+bias); also zero rowZ/colZ for the atomics.
// ---------------------------------------------------------------------------
__global__ __launch_bounds__(256) void k_subs(
        const float* __restrict__ C, const float* __restrict__ Q,
        const float* __restrict__ w4C, const float* __restrict__ w4Q,
        const float* __restrict__ bias,
        float* __restrict__ sub0, float* __restrict__ sub1,
        float* __restrict__ rowZ, float* __restrict__ colZ) {
    int bid = blockIdx.x;
    const int nb0 = B_ * (LC_ / 256);   // 128
    if (bid < nb0) {
        int b = bid / (LC_ / 256);
        int c = (bid % (LC_ / 256)) * 256 + threadIdx.x;
        const float* Cb = C + (size_t)b * D_ * LC_;
        float acc = 0.f;
        #pragma unroll 8
        for (int d = 0; d < D_; ++d) acc += Cb[(size_t)d * LC_ + c] * w4C[d];
        sub0[b * LC_ + c] = acc;
        rowZ[b * LC_ + c] = 0.f;
    } else {
        int id = bid - nb0;
        int b = id / (LQ_ / 256);
        int q = (id % (LQ_ / 256)) * 256 + threadIdx.x;
        const float* Qb = Q + (size_t)b * D_ * LQ_;
        float acc = bias[0];
        #pragma unroll 8
        for (int d = 0; d < D_; ++d) acc += Qb[(size_t)d * LQ_ + q] * w4Q[d];
        sub1[b * LQ_ + q] = acc;
        colZ[b * LQ_ + q] = 0.f;
    }
}

// ---------------------------------------------------------------------------
// k_score: 128x128 S-tile via MFMA, K=d=128 looped in 2x64 (LDS 34 KB ->
// 4 blocks/CU). Epilogue: E=exp(S-SHIFT)*qm, LDS-bounced, coalesced store.
// rowZ/colZ accumulated via shfl-reduce + atomics.
// grid (LQ/128, LC/128, B), 256 thr (4 waves, 2x2 of 64x64).
// ---------------------------------------------------------------------------
__global__ __launch_bounds__(256) void k_score(
        const ushort_t* __restrict__ Ct_bf, const ushort_t* __restrict__ Qt_bf,
        const float* __restrict__ sub0, const float* __restrict__ sub1,
        const int* __restrict__ Cmask, const int* __restrict__ Qmask,
        ushort_t* __restrict__ E_bf,
        float* __restrict__ rowZ, float* __restrict__ colZ) {
    __shared__ __align__(16) ushort_t smem[2 * 128 * 64];   // As | Bs ; reused: Etile
    ushort_t* As = smem;                 // [row c][64 d-chunk] XOR by row&7
    ushort_t* Bs = smem + 128 * 64;      // [row q][64 d-chunk]
    ushort_t* Etile = smem;              // [c][128 q] XOR-chunk, 32 KB
    __shared__ float s0s[128], s1s[128], cms[128], qms[128];
    const int b = blockIdx.z, c0 = blockIdx.y * 128, q0 = blockIdx.x * 128;
    const int tid = threadIdx.x, w = tid >> 6, lane = tid & 63;
    const int l15 = lane & 15, l4 = lane >> 4;
    const int l8 = lane >> 3, ch0 = lane & 7;
    const int wm = w >> 1, wn = w & 1;
    if (tid < 128) {
        s0s[tid] = sub0[b * LC_ + c0 + tid];
        cms[tid] = Cmask[b * LC_ + c0 + tid] ? 1.f : 0.f;
    } else {
        int t2 = tid - 128;
        s1s[t2] = sub1[b * LQ_ + q0 + t2];
        qms[t2] = Qmask[b * LQ_ + q0 + t2] ? 1.f : 0.f;
    }
    const ushort_t* Ab = Ct_bf + ((size_t)b * LC_ + c0) * D_;
    const ushort_t* Bb = Qt_bf + ((size_t)b * LQ_ + q0) * D_;
    f32x4 acc[4][4];
    const f32x4 z4 = {0.f, 0.f, 0.f, 0.f};
    #pragma unroll
    for (int i = 0; i < 4; ++i)
        #pragma unroll
        for (int j = 0; j < 4; ++j) acc[i][j] = z4;
    for (int dk = 0; dk < 2; ++dk) {                 // K-loop over d: 2 x 64
        __syncthreads();
        #pragma unroll
        for (int i = 0; i < 4; ++i) {
            int r0 = w * 32 + i * 8;
            int row = r0 + l8;
            int ch = ch0 ^ (row & 7);
            gld16(Ab + (size_t)row * 128 + dk * 64 + ch * 8, As + r0 * 64);
            gld16(Bb + (size_t)row * 128 + dk * 64 + ch * 8, Bs + r0 * 64);
        }
        __syncthreads();
        #pragma unroll
        for (int ks = 0; ks < 2; ++ks) {
            short8 af[4], bfr[4];
            #pragma unroll
            for (int mi = 0; mi < 4; ++mi) {
                int row = wm * 64 + mi * 16 + l15;
                int ch = (ks * 4 + l4) ^ (row & 7);
                af[mi] = *(const short8*)(As + row * 64 + ch * 8);
            }
            #pragma unroll
            for (int ni = 0; ni < 4; ++ni) {
                int row = wn * 64 + ni * 16 + l15;
                int ch = (ks * 4 + l4) ^ (row & 7);
                bfr[ni] = *(const short8*)(Bs + row * 64 + ch * 8);
            }
            #pragma unroll
            for (int mi = 0; mi < 4; ++mi)
                #pragma unroll
                for (int ni = 0; ni < 4; ++ni)
                    acc[mi][ni] = MFMA16(af[mi], bfr[ni], acc[mi][ni]);
        }
    }
    __syncthreads();        // all frag reads done before Etile overwrites As/Bs
    // epilogue: E = exp(S-SHIFT)*qm -> LDS tile; rowZ/colZ partials
    float rs[4][4];
    float cs[4] = {0.f, 0.f, 0.f, 0.f};
    #pragma unroll
    for (int mi = 0; mi < 4; ++mi)
        #pragma unroll
        for (int r = 0; r < 4; ++r) rs[mi][r] = 0.f;
    #pragma unroll
    for (int mi = 0; mi < 4; ++mi) {
        #pragma unroll
        for (int ni = 0; ni < 4; ++ni) {
            int q_l = wn * 64 + ni * 16 + l15;
            float qm = qms[q_l], s1v = s1s[q_l];
            #pragma unroll
            for (int r = 0; r < 4; ++r) {
                int c_l = wm * 64 + mi * 16 + l4 * 4 + r;
                float Sv = acc[mi][ni][r] + s0s[c_l] + s1v;
                float e = __expf(Sv - SHIFT_);
                ushort_t e1u = f2bf(e * qm);
                float e1f = bf2f(e1u);
                rs[mi][r] += e1f;
                cs[ni] += e1f * cms[c_l];
                Etile[c_l * 128 + (((q_l >> 3) ^ (c_l & 7)) * 8) + (q_l & 7)] = e1u;
            }
        }
    }
    __syncthreads();
    // coalesced store: each wave writes 4 complete 256B rows per pass
    #pragma unroll
    for (int pass = 0; pass < 8; ++pass) {
        int c = pass * 16 + (tid >> 4);
        int j = tid & 15;
        uint4 v = *(const uint4*)(Etile + c * 128 + ((j ^ (c & 7)) * 8));
        *(uint4*)(E_bf + ((size_t)b * LC_ + c0 + c) * LQ_ + q0 + j * 8) = v;
    }
    #pragma unroll
    for (int mi = 0; mi < 4; ++mi)
        #pragma unroll
        for (int r = 0; r < 4; ++r) {
            float v = rs[mi][r];
            v += __shfl_xor(v, 1); v += __shfl_xor(v, 2);
            v += __shfl_xor(v, 4); v += __shfl_xor(v, 8);
            if (l15 == 0)
                atomicAdd(&rowZ[b * LC_ + c0 + wm * 64 + mi * 16 + l4 * 4 + r], v);
        }
    #pragma unroll
    for (int ni = 0; ni < 4; ++ni) {
        float v = cs[ni];
        v += __shfl_xor(v, 16); v += __shfl_xor(v, 32);
        if (l4 == 0)
            atomicAdd(&colZ[b * LQ_ + q0 + wn * 64 + ni * 16 + l15], v);
    }
}

// ---------------------------------------------------------------------------
// k_tpart: Tpart[sp][b][q][d] = sum_{c in chunk sp} (E[c][q]*cm[c]) * Cb[d][c]
// q-tile 64, chunk = LC/4 = 512. A transpose-staged with conflict-free SWZA.
// grid (LQ/64, NSPLIT_, B), 256 thr (4 waves 2x2: wave = 32q x 64d).
// ---------------------------------------------------------------------------
__global__ __launch_bounds__(256) void k_tpart(
        const ushort_t* __restrict__ E_bf, const ushort_t* __restrict__ Cb_bf,
        const int* __restrict__ Cmask, float* __restrict__ Tpart, int chunk) {
    __shared__ __align__(16) ushort_t At[64 * 64];   // [q][c] chunk-XOR SWZA(q)
    __shared__ __align__(16) ushort_t Bs[128 * 64];  // [d][c] chunk-XOR (d&7)
    const int b = blockIdx.z, sp = blockIdx.y, q0 = blockIdx.x * 64;
    const int tid = threadIdx.x, w = tid >> 6, lane = tid & 63;
    const int l15 = lane & 15, l4 = lane >> 4;
    const int l8 = lane >> 3, ch0 = lane & 7;
    const int wm = w >> 1, wn = w & 1;       // wm: q-half, wn: d-half
    const int cbeg = sp * chunk;
    const ushort_t* Bb = Cb_bf + (size_t)b * D_ * LC_ + cbeg;
    const int* cm = Cmask + b * LC_;
    const int c_l = tid >> 2, qq = tid & 3;  // transpose-stage mapping
    f32x4 acc[2][4];
    const f32x4 z4 = {0.f, 0.f, 0.f, 0.f};
    #pragma unroll
    for (int i = 0; i < 2; ++i)
        #pragma unroll
        for (int j = 0; j < 4; ++j) acc[i][j] = z4;
    for (int kk = 0; kk < chunk / 64; ++kk) {
        __syncthreads();
        #pragma unroll
        for (int i = 0; i < 4; ++i) {                // B: Cb rows d, gld16 direct
            int r0 = w * 32 + i * 8;
            int row = r0 + l8;
            int ch = ch0 ^ (row & 7);
            gld16(Bb + (size_t)row * LC_ + kk * 64 + ch * 8, Bs + r0 * 64);
        }
        {                                            // A: E transpose-stage + cmask
            int cg = cbeg + kk * 64 + c_l;
            unsigned int keep = cm[cg] ? 0xFFFFFFFFu : 0u;
            const ushort_t* src = E_bf + ((size_t)b * LC_ + cg) * LQ_ + q0 + qq * 16;
            #pragma unroll
            for (int u = 0; u < 2; ++u) {
                union { uint4 v; ushort_t s[8]; } d;
                d.v = *(const uint4*)(src + u * 8);
                d.v.x &= keep; d.v.y &= keep; d.v.z &= keep; d.v.w &= keep;
                #pragma unroll
                for (int e = 0; e < 8; ++e) {
                    int q = qq * 16 + u * 8 + e;
                    At[q * 64 + (((c_l >> 3) ^ SWZA(q)) * 8) + (c_l & 7)] = d.s[e];
                }
            }
        }
        __syncthreads();
        #pragma unroll
        for (int ks = 0; ks < 2; ++ks) {
            short8 af[2], bfr[4];
            #pragma unroll
            for (int mi = 0; mi < 2; ++mi) {
                int row = wm * 32 + mi * 16 + l15;
                int ch = (ks * 4 + l4) ^ SWZA(row);
                af[mi] = *(const short8*)(At + row * 64 + ch * 8);
            }
            #pragma unroll
            for (int ni = 0; ni < 4; ++ni) {
                int row = wn * 64 + ni * 16 + l15;
                int ch = (ks * 4 + l4) ^ (row & 7);
                bfr[ni] = *(const short8*)(Bs + row * 64 + ch * 8);
            }
            #pragma unroll
            for (int mi = 0; mi < 2; ++mi)
                #pragma unroll
                for (int ni = 0; ni < 4; ++ni)
                    acc[mi][ni] = MFMA16(af[mi], bfr[ni], acc[mi][ni]);
        }
    }
    float* Tp = Tpart + (((size_t)sp * B_ + b) * LQ_ + q0) * D_;
    #pragma unroll
    for (int mi = 0; mi < 2; ++mi)
        #pragma unroll
        for (int ni = 0; ni < 4; ++ni)
            #pragma unroll
            for (int r = 0; r < 4; ++r)
                Tp[(size_t)(wm * 32 + mi * 16 + l4 * 4 + r) * D_ +
                   wn * 64 + ni * 16 + l15] = acc[mi][ni][r];
}

// ---------------------------------------------------------------------------
// k_treduce: Tt_bf[b][d][q] = bf16( sum_sp Tpart[sp][b][q][d] / colZ[q] )
// grid (LQ/64, B), 256 thr; transpose bounce via LDS.
// ---------------------------------------------------------------------------
__global__ __launch_bounds__(256) void k_treduce(
        const float* __restrict__ Tpart, const float* __restrict__ colZ,
        ushort_t* __restrict__ Tt_bf) {
    __shared__ __align__(16) ushort_t lt[128 * 72];   // [d][q], pitch 72
    const int b = blockIdx.y, q0 = blockIdx.x * 64;
    const int t = threadIdx.x;
    const int q = t >> 2, dp = t & 3;
    float r = 1.0f / (colZ[b * LQ_ + q0 + q] + 1e-30f);
    const float4* base = (const float4*)(Tpart + ((size_t)b * LQ_ + q0 + q) * D_);
    const size_t spstr = (size_t)B_ * LQ_ * D_ / 4;
    #pragma unroll
    for (int i = 0; i < 8; ++i) {
        int d4 = dp + i * 4;
        float4 s = {0.f, 0.f, 0.f, 0.f};
        #pragma unroll
        for (int sp = 0; sp < NSPLIT_; ++sp) {
            float4 v = base[(size_t)sp * spstr + d4];
            s.x += v.x; s.y += v.y; s.z += v.z; s.w += v.w;
        }
        int d = d4 * 4;
        lt[(d + 0) * 72 + q] = f2bf(s.x * r);
        lt[(d + 1) * 72 + q] = f2bf(s.y * r);
        lt[(d + 2) * 72 + q] = f2bf(s.z * r);
        lt[(d + 3) * 72 + q] = f2bf(s.w * r);
    }
    __syncthreads();
    const int d = t >> 1, half = t & 1;
    ushort_t* dst = Tt_bf + ((size_t)b * D_ + d) * LQ_ + q0 + half * 32;
    #pragma unroll
    for (int j = 0; j < 4; ++j)
        *(uint4*)(dst + j * 8) = *(const uint4*)(lt + d * 72 + half * 32 + j * 8);
}

// ---------------------------------------------------------------------------
// k_out: D1[d][c] = sum_q Qb[d][q]*E[c][q];  D2[d][c] = sum_q T'[d][q]*E[c][q]
// out = [Ct, A, Ct*A, Ct*Bm] with A = D1/rowZ, Bm = D2/rowZ.
// grid (LC/64, B), 256 thr. M=d(128), N=c(64), K=q=512 (8 iters of 64).
// ---------------------------------------------------------------------------
__global__ __launch_bounds__(256) void k_out(
        const ushort_t* __restrict__ E_bf, const ushort_t* __restrict__ Qb_bf,
        const ushort_t* __restrict__ Tt_bf, const float* __restrict__ C,
        const float* __restrict__ rowZ, float* __restrict__ out) {
    __shared__ __align__(16) ushort_t Qs[128 * 64];
    __shared__ __align__(16) ushort_t Ts[128 * 64];
    __shared__ __align__(16) ushort_t Es[64 * 64];
    __shared__ float rrs[64];
    const int b = blockIdx.y, c0 = blockIdx.x * 64;
    const int tid = threadIdx.x, w = tid >> 6, lane = tid & 63;
    const int l15 = lane & 15, l4 = lane >> 4;
    const int l8 = lane >> 3, ch0 = lane & 7;
    const int wm = w >> 1, wn = w & 1;
    if (tid < 64) rrs[tid] = 1.0f / (rowZ[b * LC_ + c0 + tid] + 1e-30f);
    const ushort_t* Qb = Qb_bf + (size_t)b * D_ * LQ_;
    const ushort_t* Tb = Tt_bf + (size_t)b * D_ * LQ_;
    const ushort_t* Eb = E_bf + ((size_t)b * LC_ + c0) * LQ_;
    f32x4 accA[4][2], accB[4][2];
    const f32x4 z4 = {0.f, 0.f, 0.f, 0.f};
    #pragma unroll
    for (int i = 0; i < 4; ++i)
        #pragma unroll
        for (int j = 0; j < 2; ++j) { accA[i][j] = z4; accB[i][j] = z4; }
    for (int kk = 0; kk < 8; ++kk) {
        __syncthreads();
        #pragma unroll
        for (int i = 0; i < 4; ++i) {
            int r0 = w * 32 + i * 8;
            int row = r0 + l8;
            int ch = ch0 ^ (row & 7);
            gld16(Qb + (size_t)row * LQ_ + kk * 64 + ch * 8, Qs + r0 * 64);
            gld16(Tb + (size_t)row * LQ_ + kk * 64 + ch * 8, Ts + r0 * 64);
        }
        #pragma unroll
        for (int i = 0; i < 2; ++i) {
            int r0 = w * 16 + i * 8;
            int row = r0 + l8;
            int ch = ch0 ^ (row & 7);
            gld16(Eb + (size_t)row * LQ_ + kk * 64 + ch * 8, Es + r0 * 64);
        }
        __syncthreads();
        #pragma unroll
        for (int ks = 0; ks < 2; ++ks) {
            short8 aq[4], at[4], be[2];
            #pragma unroll
            for (int mi = 0; mi < 4; ++mi) {
                int row = wm * 64 + mi * 16 + l15;
                int ch = (ks * 4 + l4) ^ (row & 7);
                aq[mi] = *(const short8*)(Qs + row * 64 + ch * 8);
                at[mi] = *(const short8*)(Ts + row * 64 + ch * 8);
            }
            #pragma unroll
            for (int ni = 0; ni < 2; ++ni) {
                int row = wn * 32 + ni * 16 + l15;
                int ch = (ks * 4 + l4) ^ (row & 7);
                be[ni] = *(const short8*)(Es + row * 64 + ch * 8);
            }
            #pragma unroll
            for (int mi = 0; mi < 4; ++mi)
                #pragma unroll
                for (int ni = 0; ni < 2; ++ni) {
                    accA[mi][ni] = MFMA16(aq[mi], be[ni], accA[mi][ni]);
                    accB[mi][ni] = MFMA16(at[mi], be[ni], accB[mi][ni]);
                }
        }
    }
    #pragma unroll
    for (int mi = 0; mi < 4; ++mi)
        #pragma unroll
        for (int ni = 0; ni < 2; ++ni) {
            int c_l = wn * 32 + ni * 16 + l15;
            int cg = c0 + c_l;
            float rr = rrs[c_l];
            #pragma unroll
            for (int r = 0; r < 4; ++r) {
                int d = wm * 64 + mi * 16 + l4 * 4 + r;
                float ct = C[((size_t)b * D_ + d) * LC_ + cg];
                float av = accA[mi][ni][r] * rr;
                float bv = accB[mi][ni][r] * rr;
                size_t o = ((size_t)b * 4 * D_ + d) * LC_ + cg;
                out[o] = ct;
                out[o + (size_t)D_ * LC_] = av;
                out[o + (size_t)2 * D_ * LC_] = ct * av;
                out[o + (size_t)3 * D_ * LC_] = ct * bv;
            }
        }
}

// ---------------------------------------------------------------------------
extern "C" void kernel_launch(void* const* d_in, const int* in_sizes, int n_in,
                              void* d_out, int out_size, void* d_ws, size_t ws_size,
                              hipStream_t stream) {
    (void)in_sizes; (void)n_in; (void)out_size; (void)ws_size;
    const float* C     = (const float*)d_in[0];
    const float* Q     = (const float*)d_in[1];
    const int*   Cmask = (const int*)d_in[2];
    const int*   Qmask = (const int*)d_in[3];
    const float* w4C   = (const float*)d_in[4];
    const float* w4Q   = (const float*)d_in[5];
    const float* w4mlu = (const float*)d_in[6];
    const float* bias  = (const float*)d_in[7];
    float* out = (float*)d_out;

    char* p = (char*)d_ws;
    auto alloc = [&](size_t bytes) -> void* {
        void* r = (void*)p; p += (bytes + 255) & ~(size_t)255; return r;
    };
    ushort_t* Ct_bf = (ushort_t*)alloc((size_t)B_ * LC_ * D_ * 2);   // [b][c][d] *w4mlu
    ushort_t* Qt_bf = (ushort_t*)alloc((size_t)B_ * LQ_ * D_ * 2);   // [b][q][d]
    ushort_t* Cb_bf = (ushort_t*)alloc((size_t)B_ * D_ * LC_ * 2);   // [b][d][c]
    ushort_t* Qb_bf = (ushort_t*)alloc((size_t)B_ * D_ * LQ_ * 2);   // [b][d][q]
    ushort_t* E_bf  = (ushort_t*)alloc((size_t)B_ * LC_ * LQ_ * 2);  // exp, q-masked
    ushort_t* Tt_bf = (ushort_t*)alloc((size_t)B_ * D_ * LQ_ * 2);   // [b][d][q]
    float* sub0 = (float*)alloc((size_t)B_ * LC_ * 4);
    float* sub1 = (float*)alloc((size_t)B_ * LQ_ * 4);
    float* rowZ = (float*)alloc((size_t)B_ * LC_ * 4);
    float* colZ = (float*)alloc((size_t)B_ * LQ_ * 4);
    float* Tpart = (float*)alloc((size_t)NSPLIT_ * B_ * LQ_ * D_ * 4);  // 16.7 MB

    const int chunk = LC_ / NSPLIT_;   // 512

    k_prep<<<dim3(LC_ / 64, 2, B_), 256, 0, stream>>>(C, w4mlu, Cb_bf, Ct_bf, LC_);
    k_prep<<<dim3(LQ_ / 64, 2, B_), 256, 0, stream>>>(Q, nullptr, Qb_bf, Qt_bf, LQ_);
    k_subs<<<B_ * (LC_ / 256) + B_ * (LQ_ / 256), 256, 0, stream>>>(
        C, Q, w4C, w4Q, bias, sub0, sub1, rowZ, colZ);
    k_score<<<dim3(LQ_ / 128, LC_ / 128, B_), 256, 0, stream>>>(
        Ct_bf, Qt_bf, sub0, sub1, Cmask, Qmask, E_bf, rowZ, colZ);
    k_tpart<<<dim3(LQ_ / 64, NSPLIT_, B_), 256, 0, stream>>>(
        E_bf, Cb_bf, Cmask, Tpart, chunk);
    k_treduce<<<dim3(LQ_ / 64, B_), 256, 0, stream>>>(Tpart, colZ, Tt_bf);
    k_out<<<dim3(LC_ / 64, B_), 256, 0, stream>>>(E_bf, Qb_bf, Tt_bf, C, rowZ, out);
}